// Round 1
// baseline (89007.080 us; speedup 1.0000x reference)
//
#include <hip/hip_runtime.h>
#include <hip/hip_bf16.h>
#include <cstdint>
#include <cstddef>

// Problem constants (from setup_inputs)
constexpr int B_  = 128;
constexpr int T_  = 400;
constexpr int TE_ = 1600;
constexpr int V_  = 31;
constexpr int EMB_= 256;
constexpr int H_  = 512;
constexpr int P_  = 256;
constexpr int G4_ = 2048;   // 4*H
constexpr int SOS = 1;

// ---------- helpers ----------
__device__ __forceinline__ float bf2f(unsigned short u) {
    return __uint_as_float(((unsigned int)u) << 16);
}
__device__ __forceinline__ unsigned short f2bf(float f) {
    unsigned int u = __float_as_uint(f);
    unsigned int r = u + 0x7fffu + ((u >> 16) & 1u);   // RNE
    return (unsigned short)(r >> 16);
}
__device__ __forceinline__ float sigf(float x) { return 1.0f / (1.0f + expf(-x)); }
__device__ __forceinline__ float dotu(unsigned int u, float qa, float qb) {
    return bf2f((unsigned short)(u & 0xffffu)) * qa + bf2f((unsigned short)(u >> 16)) * qb;
}

// ---------- one-time per call: fp32 -> bf16 copies of keys/values ----------
__global__ void cvt_kernel(const float4* __restrict__ k4, const float4* __restrict__ v4,
                           ushort4* __restrict__ ko, ushort4* __restrict__ vo, int n4) {
    int stride = gridDim.x * blockDim.x;
    for (int i = blockIdx.x * blockDim.x + threadIdx.x; i < n4; i += stride) {
        float4 a = k4[i];
        ushort4 oa; oa.x = f2bf(a.x); oa.y = f2bf(a.y); oa.z = f2bf(a.z); oa.w = f2bf(a.w);
        ko[i] = oa;
        float4 b = v4[i];
        ushort4 ob; ob.x = f2bf(b.x); ob.y = f2bf(b.y); ob.z = f2bf(b.z); ob.w = f2bf(b.w);
        vo[i] = ob;
    }
}

__global__ void zero_kernel(float* __restrict__ p, int n) {
    int i = blockIdx.x * blockDim.x + threadIdx.x;
    if (i < n) p[i] = 0.f;
}

// ---------- LSTM gate GEMM ----------
// Computes gates_out[b][j] = bias[j] + sum_{k<512} src[b,k] * W[j,k]
// blockIdx.z selects split: z=0 -> (x, Wih, bih, g0), z=1 -> (h, Whh, bhh, g1).
// Layer 1's x is gathered on the fly from E[token] (k<256) and ctx (k>=256) when xsrc==nullptr.
// Tile: 32b x 32j, BK=32, 256 threads, 4 outputs/thread, grid = 64x4x2 = 512 blocks.
__global__ __launch_bounds__(256) void lstm_gemm(
    const float* __restrict__ xsrc, const float* __restrict__ hsrc,
    const float* __restrict__ Wih, const float* __restrict__ bih,
    const float* __restrict__ Whh, const float* __restrict__ bhh,
    const float* __restrict__ Emb, const float* __restrict__ ctx,
    const int* __restrict__ y, int t,
    float* __restrict__ g0, float* __restrict__ g1)
{
    const int tid = threadIdx.x;
    const int j0 = blockIdx.x * 32;
    const int b0 = blockIdx.y * 32;
    const int bz = blockIdx.z;
    const float* W   = bz ? Whh : Wih;
    const float* src = bz ? hsrc : xsrc;

    __shared__ float Xs[32][34];
    __shared__ float Ws[32][34];

    const int tx = tid & 15, ty = tid >> 4;
    float a00 = 0.f, a01 = 0.f, a10 = 0.f, a11 = 0.f;

    for (int c = 0; c < 16; ++c) {
        const int k0 = c * 32;
        int idx = tid;
#pragma unroll
        for (int i = 0; i < 4; ++i, idx += 256) {
            const int kk = idx & 31, rr = idx >> 5;
            float xv;
            if (src) {
                xv = src[(b0 + rr) * H_ + k0 + kk];
            } else {                    // layer-1 gather: concat(E[token], ctx)
                const int k = k0 + kk;
                const int bb = b0 + rr;
                const int tok = (t == 0) ? SOS : y[bb * T_ + t - 1];
                xv = (k < EMB_) ? Emb[tok * EMB_ + k] : ctx[bb * P_ + (k - EMB_)];
            }
            Xs[kk][rr] = xv;
            Ws[kk][rr] = W[(j0 + rr) * H_ + k0 + kk];
        }
        __syncthreads();
#pragma unroll
        for (int kk = 0; kk < 32; ++kk) {
            const float2 xv = *(const float2*)&Xs[kk][2 * ty];
            const float2 wv = *(const float2*)&Ws[kk][2 * tx];
            a00 = fmaf(xv.x, wv.x, a00);
            a01 = fmaf(xv.x, wv.y, a01);
            a10 = fmaf(xv.y, wv.x, a10);
            a11 = fmaf(xv.y, wv.y, a11);
        }
        __syncthreads();
    }
    const float* bias = bz ? bhh : bih;
    float* out = bz ? g1 : g0;
    const int b = b0 + 2 * ty, j = j0 + 2 * tx;
    const float bj0 = bias[j], bj1 = bias[j + 1];
    out[(size_t)b * G4_ + j]           = a00 + bj0;
    out[(size_t)b * G4_ + j + 1]       = a01 + bj1;
    out[(size_t)(b + 1) * G4_ + j]     = a10 + bj0;
    out[(size_t)(b + 1) * G4_ + j + 1] = a11 + bj1;
}

// ---------- pointwise LSTM update (layers 1,2) ----------
__global__ void lstm_point(const float* __restrict__ g0, const float* __restrict__ g1,
                           float* __restrict__ h, float* __restrict__ c) {
    const int i = blockIdx.x * 256 + threadIdx.x;   // < 128*512
    const int b = i >> 9, j = i & 511;
    const float* p0 = g0 + (size_t)b * G4_ + j;
    const float* p1 = g1 + (size_t)b * G4_ + j;
    const float gi = p0[0]    + p1[0];
    const float gf = p0[512]  + p1[512];
    const float gg = p0[1024] + p1[1024];
    const float go = p0[1536] + p1[1536];
    const float cc = sigf(gf) * c[i] + sigf(gi) * tanhf(gg);
    const float hh = sigf(go) * tanhf(cc);
    c[i] = cc; h[i] = hh;
}

// ---------- layer-3 pointwise + q projection + zero S/ctx ----------
__global__ __launch_bounds__(256) void lstm_point3_q(
    const float* __restrict__ g0, const float* __restrict__ g1,
    float* __restrict__ h3, float* __restrict__ c3,
    const float* __restrict__ Wq, const float* __restrict__ bq,
    float* __restrict__ q, float* __restrict__ S, float* __restrict__ ctx)
{
    const int b = blockIdx.x, tid = threadIdx.x;
    __shared__ float hs[H_];
    for (int jj = tid; jj < H_; jj += 256) {
        const int i = b * H_ + jj;
        const float* p0 = g0 + (size_t)b * G4_ + jj;
        const float* p1 = g1 + (size_t)b * G4_ + jj;
        const float gi = p0[0]    + p1[0];
        const float gf = p0[512]  + p1[512];
        const float gg = p0[1024] + p1[1024];
        const float go = p0[1536] + p1[1536];
        const float cc = sigf(gf) * c3[i] + sigf(gi) * tanhf(gg);
        const float hh = sigf(go) * tanhf(cc);
        c3[i] = cc; h3[i] = hh; hs[jj] = hh;
    }
    __syncthreads();
    // q[b][p] = bq[p] + h3[b] . Wq[p]
    float acc = bq[tid];
    const float4* wr = (const float4*)(Wq + (size_t)tid * H_);
#pragma unroll 8
    for (int k4 = 0; k4 < H_ / 4; ++k4) {
        const float4 w4 = wr[k4];
        const float4 x4 = *(const float4*)&hs[k4 * 4];
        acc = fmaf(w4.x, x4.x, acc); acc = fmaf(w4.y, x4.y, acc);
        acc = fmaf(w4.z, x4.z, acc); acc = fmaf(w4.w, x4.w, acc);
    }
    q[b * P_ + tid] = acc;
    ctx[b * P_ + tid] = 0.f;       // consumed only after att_ctx accumulates
    if (tid == 0) S[b] = 0.f;
}

// ---------- attention pass 1: e = exp(q.k), partial sums -> S ----------
// grid (10, B): 10 chunks of 160 rows. 256 thr = 8 groups of 32 lanes; one row per group-iter.
template<bool BF>
__global__ __launch_bounds__(256) void att_energy(
    const float* __restrict__ q, const void* __restrict__ keysv,
    float* __restrict__ e, float* __restrict__ S)
{
    const int b    = blockIdx.y;
    const int base = blockIdx.x * 160;
    const int tid  = threadIdx.x;
    const int lane = tid & 31;
    const int g    = tid >> 5;

    float qv[8];
    {
        const float4* qp = (const float4*)(q + b * P_ + lane * 8);
        const float4 q0 = qp[0], q1 = qp[1];
        qv[0]=q0.x; qv[1]=q0.y; qv[2]=q0.z; qv[3]=q0.w;
        qv[4]=q1.x; qv[5]=q1.y; qv[6]=q1.z; qv[7]=q1.w;
    }
    float wsum = 0.f;
#pragma unroll 2
    for (int ri = 0; ri < 20; ++ri) {
        const int row = base + g + ri * 8;
        float part;
        if (BF) {
            const uint4 kv = *(const uint4*)((const unsigned short*)keysv +
                                ((size_t)b * TE_ + row) * P_ + lane * 8);
            part  = dotu(kv.x, qv[0], qv[1]);
            part += dotu(kv.y, qv[2], qv[3]);
            part += dotu(kv.z, qv[4], qv[5]);
            part += dotu(kv.w, qv[6], qv[7]);
        } else {
            const float4* kp = (const float4*)((const float*)keysv +
                                ((size_t)b * TE_ + row) * P_ + lane * 8);
            const float4 k0 = kp[0], k1 = kp[1];
            part  = k0.x*qv[0] + k0.y*qv[1] + k0.z*qv[2] + k0.w*qv[3];
            part += k1.x*qv[4] + k1.y*qv[5] + k1.z*qv[6] + k1.w*qv[7];
        }
        part += __shfl_xor(part, 16);
        part += __shfl_xor(part, 8);
        part += __shfl_xor(part, 4);
        part += __shfl_xor(part, 2);
        part += __shfl_xor(part, 1);
        const float ex = expf(part);   // |energy| small; no max-subtraction needed
        if (lane == 0) e[b * TE_ + row] = ex;
        wsum += ex;
    }
    if (lane == 0) atomicAdd(&S[b], wsum);
}

// ---------- attention pass 2: w = e/S -> attn_out; ctx += w.values ----------
template<bool BF>
__global__ __launch_bounds__(256) void att_ctx(
    const float* __restrict__ e, const float* __restrict__ S,
    const void* __restrict__ valsv, float* __restrict__ ctx,
    float* __restrict__ attn, int t)
{
    const int b    = blockIdx.y;
    const int base = blockIdx.x * 160;
    const int tid  = threadIdx.x;
    __shared__ float ws_[160];
    const float rS = 1.0f / S[b];
    for (int i = tid; i < 160; i += 256) {
        const float w = e[b * TE_ + base + i] * rS;
        attn[((size_t)b * T_ + t) * TE_ + base + i] = w;
        ws_[i] = w;
    }
    __syncthreads();
    float acc = 0.f;
    if (BF) {
        const unsigned short* vp = (const unsigned short*)valsv +
                                   ((size_t)b * TE_ + base) * P_ + tid;
#pragma unroll 4
        for (int r = 0; r < 160; ++r)
            acc = fmaf(ws_[r], bf2f(vp[(size_t)r * P_]), acc);
    } else {
        const float* vp = (const float*)valsv + ((size_t)b * TE_ + base) * P_ + tid;
#pragma unroll 4
        for (int r = 0; r < 160; ++r)
            acc = fmaf(ws_[r], vp[(size_t)r * P_], acc);
    }
    atomicAdd(&ctx[b * P_ + tid], acc);
}

// ---------- output head: logits = tanh([h3|ctx] Wc^T + bc) E^T + bprob ----------
__global__ __launch_bounds__(256) void out_kernel(
    const float* __restrict__ h3, const float* __restrict__ ctx,
    const float* __restrict__ Wc, const float* __restrict__ bc,
    const float* __restrict__ Emb, const float* __restrict__ bprob,
    float* __restrict__ raw, int t)
{
    const int b0 = blockIdx.x * 4;
    const int tid = threadIdx.x;
    __shared__ float cdn[4][768];
    __shared__ float t0[4][256];
    for (int i = tid; i < 4 * 768; i += 256) {
        const int bb = i / 768, k = i - bb * 768;
        cdn[bb][k] = (k < H_) ? h3[(b0 + bb) * H_ + k] : ctx[(b0 + bb) * P_ + (k - H_)];
    }
    __syncthreads();
    float a0 = bc[tid], a1 = a0, a2 = a0, a3 = a0;
    const float4* wr = (const float4*)(Wc + (size_t)tid * 768);
#pragma unroll 4
    for (int k4 = 0; k4 < 192; ++k4) {
        const float4 w4 = wr[k4];
        const float4 x0 = *(const float4*)&cdn[0][k4 * 4];
        const float4 x1 = *(const float4*)&cdn[1][k4 * 4];
        const float4 x2 = *(const float4*)&cdn[2][k4 * 4];
        const float4 x3 = *(const float4*)&cdn[3][k4 * 4];
        a0 += w4.x*x0.x + w4.y*x0.y + w4.z*x0.z + w4.w*x0.w;
        a1 += w4.x*x1.x + w4.y*x1.y + w4.z*x1.z + w4.w*x1.w;
        a2 += w4.x*x2.x + w4.y*x2.y + w4.z*x2.z + w4.w*x2.w;
        a3 += w4.x*x3.x + w4.y*x3.y + w4.z*x3.z + w4.w*x3.w;
    }
    t0[0][tid] = tanhf(a0); t0[1][tid] = tanhf(a1);
    t0[2][tid] = tanhf(a2); t0[3][tid] = tanhf(a3);
    __syncthreads();
    if (tid < 4 * V_) {
        const int bb = tid / V_, v = tid - bb * V_;
        float acc = bprob[v];
        const float4* er = (const float4*)(Emb + v * EMB_);
#pragma unroll 8
        for (int k4 = 0; k4 < EMB_ / 4; ++k4) {
            const float4 e4 = er[k4];
            const float4 x4 = *(const float4*)&t0[bb][k4 * 4];
            acc += e4.x*x4.x + e4.y*x4.y + e4.z*x4.z + e4.w*x4.w;
        }
        raw[((size_t)(b0 + bb) * T_ + t) * V_ + v] = acc;
    }
}

extern "C" void kernel_launch(void* const* d_in, const int* in_sizes, int n_in,
                              void* d_out, int out_size, void* d_ws, size_t ws_size,
                              hipStream_t stream)
{
    (void)in_sizes; (void)n_in; (void)out_size;
    const int*   y      = (const int*)  d_in[0];
    const float* keys   = (const float*)d_in[1];
    const float* values = (const float*)d_in[2];
    const float* E      = (const float*)d_in[3];
    const float* Wih1 = (const float*)d_in[4];  const float* bih1 = (const float*)d_in[5];
    const float* Whh1 = (const float*)d_in[6];  const float* bhh1 = (const float*)d_in[7];
    const float* Wih2 = (const float*)d_in[8];  const float* bih2 = (const float*)d_in[9];
    const float* Whh2 = (const float*)d_in[10]; const float* bhh2 = (const float*)d_in[11];
    const float* Wih3 = (const float*)d_in[12]; const float* bih3 = (const float*)d_in[13];
    const float* Whh3 = (const float*)d_in[14]; const float* bhh3 = (const float*)d_in[15];
    const float* Wq   = (const float*)d_in[16]; const float* bq   = (const float*)d_in[17];
    const float* Wc   = (const float*)d_in[18]; const float* bc   = (const float*)d_in[19];
    const float* bprob= (const float*)d_in[20];

    float* raw  = (float*)d_out;
    float* attn = raw + (size_t)B_ * T_ * V_;

    // workspace carve (fp32 scratch first; states h1..c3,ctx are contiguous for one zero pass)
    float* f  = (float*)d_ws;
    float* h1 = f; f += B_ * H_;
    float* c1 = f; f += B_ * H_;
    float* h2 = f; f += B_ * H_;
    float* c2 = f; f += B_ * H_;
    float* h3 = f; f += B_ * H_;
    float* c3 = f; f += B_ * H_;
    float* ctx= f; f += B_ * P_;          // end of zero region
    const int zeroN = 6 * B_ * H_ + B_ * P_;   // 425984
    float* q  = f; f += B_ * P_;
    float* g0 = f; f += B_ * G4_;
    float* g1 = f; f += B_ * G4_;
    float* e  = f; f += B_ * TE_;
    float* S  = f; f += 128;
    const size_t scratch_bytes = (size_t)((char*)f - (char*)d_ws);

    unsigned short* kb = (unsigned short*)((char*)d_ws + scratch_bytes);
    unsigned short* vb = kb + (size_t)B_ * TE_ * P_;
    const size_t need_bf = scratch_bytes + (size_t)B_ * TE_ * P_ * 2 * sizeof(unsigned short);
    const bool use_bf = (ws_size >= need_bf);   // constant across calls -> graph-safe

    if (use_bf) {
        cvt_kernel<<<2048, 256, 0, stream>>>((const float4*)keys, (const float4*)values,
                                             (ushort4*)kb, (ushort4*)vb,
                                             (int)((size_t)B_ * TE_ * P_ / 4));
    }
    zero_kernel<<<(zeroN + 255) / 256, 256, 0, stream>>>((float*)d_ws, zeroN);

    for (int t = 0; t < T_; ++t) {
        lstm_gemm<<<dim3(64, 4, 2), 256, 0, stream>>>(nullptr, h1, Wih1, bih1, Whh1, bhh1,
                                                      E, ctx, y, t, g0, g1);
        lstm_point<<<B_ * H_ / 256, 256, 0, stream>>>(g0, g1, h1, c1);
        lstm_gemm<<<dim3(64, 4, 2), 256, 0, stream>>>(h1, h2, Wih2, bih2, Whh2, bhh2,
                                                      E, ctx, y, t, g0, g1);
        lstm_point<<<B_ * H_ / 256, 256, 0, stream>>>(g0, g1, h2, c2);
        lstm_gemm<<<dim3(64, 4, 2), 256, 0, stream>>>(h2, h3, Wih3, bih3, Whh3, bhh3,
                                                      E, ctx, y, t, g0, g1);
        lstm_point3_q<<<B_, 256, 0, stream>>>(g0, g1, h3, c3, Wq, bq, q, S, ctx);
        if (use_bf) {
            att_energy<true ><<<dim3(10, B_), 256, 0, stream>>>(q, kb, e, S);
            att_ctx   <true ><<<dim3(10, B_), 256, 0, stream>>>(e, S, vb, ctx, attn, t);
        } else {
            att_energy<false><<<dim3(10, B_), 256, 0, stream>>>(q, keys, e, S);
            att_ctx   <false><<<dim3(10, B_), 256, 0, stream>>>(e, S, values, ctx, attn, t);
        }
        out_kernel<<<B_ / 4, 256, 0, stream>>>(h3, ctx, Wc, bc, E, bprob, raw, t);
    }
}